// Round 1
// baseline (198.448 us; speedup 1.0000x reference)
//
#include <hip/hip_runtime.h>
#include <hip/hip_bf16.h>

// Problem constants (from reference setup_inputs)
#define NPTS   20000
#define BATCH  2
#define NQ     2048          // P
#define NS     32            // NSAMPLE
#define NC     64            // feature channels
#define NCOUT  67            // 3 + 64
#define NQTOT  (BATCH * NQ)  // 4096 queries

// new_features elements = B * 67 * P * S
#define NF_ELEMS (BATCH * NCOUT * NQ * NS)   // 17,563,648

// -------- exact-fp32 helpers (no FMA contraction; replicate numpy order) ----
__device__ __forceinline__ float sq3(float a, float b, float c) {
    // (a*a + b*b) + c*c, all rn, no fma
    return __fadd_rn(__fadd_rn(__fmul_rn(a, a), __fmul_rn(b, b)), __fmul_rn(c, c));
}

// ---------------------------------------------------------------------------
// Kernel 1: transpose features (C, N) -> featT (N, C) via LDS tile
// ---------------------------------------------------------------------------
__global__ void feat_transpose_kernel(const float* __restrict__ features,
                                      float* __restrict__ featT) {
    __shared__ float tile[64][65];  // +1 pad: conflict-free column reads
    const int n0 = blockIdx.x * 64;
    const int t  = threadIdx.x;     // 256 threads
    const int nn   = t & 63;
    const int cgrp = t >> 6;        // 0..3

    // read: lanes vary nn -> coalesced rows of features
    for (int k = 0; k < 16; ++k) {
        const int cc = cgrp * 16 + k;   // 0..63
        const int n  = n0 + nn;
        if (n < NPTS) tile[cc][nn] = features[cc * NPTS + n];
    }
    __syncthreads();
    // write: lanes vary cc2 -> coalesced rows of featT
    const int cc2  = t & 63;
    const int ngrp = t >> 6;
    for (int k = 0; k < 16; ++k) {
        const int nn2 = ngrp * 16 + k;
        const int n   = n0 + nn2;
        if (n < NPTS) featT[n * NC + cc2] = tile[cc2][nn2];
    }
}

// ---------------------------------------------------------------------------
// Kernel 2: ball query — one wave per query, ballot + prefix-popcount keeps
// the first NS in-ball indices in ascending point order (== top_k(-scores)).
// Writes idx to ws and idn (as 0.0f/1.0f) to the tail of d_out.
// ---------------------------------------------------------------------------
__global__ __launch_bounds__(256) void ball_query_kernel(
        const float* __restrict__ xyz,      // (N,3)
        const float* __restrict__ new_xyz,  // (B*P,3) flat
        int*   __restrict__ idxOut,         // (B*P, NS)
        float* __restrict__ idnOut) {       // (B*P, NS) written as float
    const float R2 = (float)(0.08 * 0.08);

    const int wid  = threadIdx.x >> 6;      // wave in block: 0..3
    const int lane = threadIdx.x & 63;
    const int q    = blockIdx.x * 4 + wid;  // grid = 1024 -> q < 4096

    __shared__ int buf[4][NS];

    const float qx = new_xyz[q * 3 + 0];
    const float qy = new_xyz[q * 3 + 1];
    const float qz = new_xyz[q * 3 + 2];
    const float q2 = sq3(qx, qy, qz);

    int cnt = 0;  // wave-uniform (derived from ballot)
    for (int base = 0; base < NPTS; base += 64) {
        const int i = base + lane;
        bool inball = false;
        if (i < NPTS) {
            const float px = xyz[i * 3 + 0];
            const float py = xyz[i * 3 + 1];
            const float pz = xyz[i * 3 + 2];
            const float x2 = sq3(px, py, pz);
            const float cross = __fadd_rn(
                __fadd_rn(__fmul_rn(qx, px), __fmul_rn(qy, py)),
                __fmul_rn(qz, pz));
            const float d2 = __fsub_rn(__fadd_rn(q2, x2), __fmul_rn(2.0f, cross));
            inball = d2 < R2;
        }
        const unsigned long long m = __ballot(inball);
        if (inball) {
            const unsigned long long lt = (1ull << lane) - 1ull;
            const int pos = cnt + __popcll(m & lt);
            if (pos < NS) buf[wid][pos] = i;
        }
        cnt += __popcll(m);
        if (cnt >= NS) break;   // wave-uniform break
    }

    __syncthreads();  // make buf[] writes visible (also orders LDS ops)

    if (lane < NS) {
        const int nf = (cnt < NS) ? cnt : NS;
        int   v;
        float fl;
        if (nf == 0) { v = 0; fl = 1.0f; }            // empty ball: idx=0, idn=1
        else {
            v  = (lane < nf) ? buf[wid][lane] : buf[wid][0];
            fl = (lane < nf) ? 1.0f : 0.0f;
        }
        idxOut[q * NS + lane] = v;
        idnOut[q * NS + lane] = fl;
    }
}

// ---------------------------------------------------------------------------
// Kernel 3: group — one block (256 thr) per query.
// out[b, c, p, s]: c<3 -> xyz[idx][c] - new_xyz[b,p,c]; else features[c-3, idx]
// ---------------------------------------------------------------------------
__global__ __launch_bounds__(256) void group_kernel(
        const float* __restrict__ xyz,
        const float* __restrict__ new_xyz,
        const float* __restrict__ features,  // (C,N) original
        const float* __restrict__ featT,     // (N,C) transposed (may be null)
        const int*   __restrict__ idx,
        float* __restrict__ out,
        int haveFeatT) {
    const int q = blockIdx.x;         // 0..4095
    const int b = q >> 11;            // q / 2048
    const int p = q & (NQ - 1);

    __shared__ int   sidx[NS];
    __shared__ float sq[3];

    const int t = threadIdx.x;
    if (t < NS) sidx[t] = idx[q * NS + t];
    if (t < 3)  sq[t]   = new_xyz[q * 3 + t];
    __syncthreads();

    // xyz part: 3 channels x 32 samples = 96 values
    if (t < 96) {
        const int d = t >> 5;         // 0..2
        const int s = t & 31;
        const int id = sidx[s];
        const int o = ((b * NCOUT + d) * NQ + p) * NS + s;
        out[o] = __fsub_rn(xyz[id * 3 + d], sq[d]);
    }

    // feature part: 64 channels x 32 samples; lanes: s contiguous -> coalesced writes
    const int s  = t & 31;
    const int c4 = t >> 5;            // 0..7 (float4 chunk)
    const int id = sidx[s];
    const int CH_STRIDE = NQ * NS;    // 65536

    if (haveFeatT) {
        const float4* ft = (const float4*)featT;
        #pragma unroll
        for (int h = 0; h < 2; ++h) {
            const int cc4 = c4 + h * 8;            // 0..15
            const float4 v = ft[id * (NC / 4) + cc4];
            const int cbase = cc4 * 4;
            const int o = ((b * NCOUT + 3 + cbase) * NQ + p) * NS + s;
            out[o]                 = v.x;
            out[o + 1 * CH_STRIDE] = v.y;
            out[o + 2 * CH_STRIDE] = v.z;
            out[o + 3 * CH_STRIDE] = v.w;
        }
    } else {
        #pragma unroll
        for (int h = 0; h < 2; ++h) {
            const int cbase = (c4 + h * 8) * 4;
            #pragma unroll
            for (int k = 0; k < 4; ++k) {
                const int c = cbase + k;
                const int o = ((b * NCOUT + 3 + c) * NQ + p) * NS + s;
                out[o] = features[c * NPTS + id];
            }
        }
    }
}

extern "C" void kernel_launch(void* const* d_in, const int* in_sizes, int n_in,
                              void* d_out, int out_size, void* d_ws, size_t ws_size,
                              hipStream_t stream) {
    const float* xyz      = (const float*)d_in[0];  // (20000,3)
    const float* new_xyz  = (const float*)d_in[1];  // (2,2048,3)
    const float* features = (const float*)d_in[2];  // (64,20000)

    float* out     = (float*)d_out;
    float* idn_out = out + NF_ELEMS;                // idn tail, written as float

    // workspace layout: [idx: 4096*32 int = 512 KiB][featT: 20000*64 f32 = 5 MB]
    const size_t IDX_BYTES   = (size_t)NQTOT * NS * sizeof(int);   // 524288
    const size_t FEATT_BYTES = (size_t)NPTS * NC * sizeof(float);  // 5120000
    int*   d_idx   = (int*)d_ws;
    float* d_featT = (float*)((char*)d_ws + IDX_BYTES);
    const int haveFeatT = (ws_size >= IDX_BYTES + FEATT_BYTES) ? 1 : 0;

    if (haveFeatT) {
        feat_transpose_kernel<<<(NPTS + 63) / 64, 256, 0, stream>>>(features, d_featT);
    }

    ball_query_kernel<<<NQTOT / 4, 256, 0, stream>>>(xyz, new_xyz, d_idx, idn_out);

    group_kernel<<<NQTOT, 256, 0, stream>>>(xyz, new_xyz, features,
                                            haveFeatT ? d_featT : nullptr,
                                            d_idx, out, haveFeatT);
}

// Round 2
// 107.053 us; speedup vs baseline: 1.8537x; 1.8537x over previous
//
#include <hip/hip_runtime.h>
#include <hip/hip_bf16.h>

// Problem constants (from reference setup_inputs)
#define NPTS   20000
#define BATCH  2
#define NQ     2048          // P
#define NS     32            // NSAMPLE
#define NC     64            // feature channels
#define NCOUT  67            // 3 + 64
#define NQTOT  (BATCH * NQ)  // 4096 queries
#define NF_ELEMS (BATCH * NCOUT * NQ * NS)   // 17,563,648

// Spatial grid: cell edge 1/12 = 0.08333 >= radius 0.08 -> 3x3x3 neighborhood covers ball
#define GRID   12
#define NCELL  (GRID * GRID * GRID)   // 1728
#define CAND_CAP 128                  // max in-ball candidates kept per query (mean ~43)

// -------- exact-fp32 helpers (no FMA contraction; replicate numpy order) ----
__device__ __forceinline__ float sq3(float a, float b, float c) {
    return __fadd_rn(__fadd_rn(__fmul_rn(a, a), __fmul_rn(b, b)), __fmul_rn(c, c));
}

// ---------------------------------------------------------------------------
// Grid build: zero -> count -> scan -> scatter
// ---------------------------------------------------------------------------
__global__ __launch_bounds__(256) void zero_counts_kernel(int* __restrict__ cnt) {
    const int t = threadIdx.x;
    #pragma unroll
    for (int i = 0; i < 7; ++i) {
        const int c = t * 7 + i;
        if (c < NCELL) cnt[c] = 0;
    }
}

__global__ __launch_bounds__(256) void cell_count_kernel(
        const float* __restrict__ xyz, int* __restrict__ cellOf,
        int* __restrict__ cnt) {
    const int n = blockIdx.x * 256 + threadIdx.x;
    if (n >= NPTS) return;
    const float x = xyz[n * 3 + 0];
    const float y = xyz[n * 3 + 1];
    const float z = xyz[n * 3 + 2];
    const int cx = min(max((int)(x * (float)GRID), 0), GRID - 1);
    const int cy = min(max((int)(y * (float)GRID), 0), GRID - 1);
    const int cz = min(max((int)(z * (float)GRID), 0), GRID - 1);
    const int cell = (cx * GRID + cy) * GRID + cz;
    cellOf[n] = cell;
    atomicAdd(&cnt[cell], 1);
}

__global__ __launch_bounds__(256) void scan_kernel(
        const int* __restrict__ cnt, int* __restrict__ start,
        int* __restrict__ cursor) {
    __shared__ int s[256];
    const int t = threadIdx.x;
    int loc[7];
    int sum = 0;
    #pragma unroll
    for (int i = 0; i < 7; ++i) {
        const int c = t * 7 + i;
        const int v = (c < NCELL) ? cnt[c] : 0;
        loc[i] = sum;            // prefix within this thread's chunk
        sum += v;
    }
    s[t] = sum;
    __syncthreads();
    for (int off = 1; off < 256; off <<= 1) {   // Hillis-Steele inclusive scan
        const int v = (t >= off) ? s[t - off] : 0;
        __syncthreads();
        s[t] += v;
        __syncthreads();
    }
    const int excl = s[t] - sum;
    #pragma unroll
    for (int i = 0; i < 7; ++i) {
        const int c = t * 7 + i;
        if (c < NCELL) {
            const int val = excl + loc[i];
            start[c]  = val;
            cursor[c] = val;
        }
    }
    if (t == 255) start[NCELL] = s[255];   // total (= NPTS)
}

__global__ __launch_bounds__(256) void scatter_kernel(
        const float* __restrict__ xyz, const int* __restrict__ cellOf,
        int* __restrict__ cursor, float4* __restrict__ packed) {
    const int n = blockIdx.x * 256 + threadIdx.x;
    if (n >= NPTS) return;
    const int pos = atomicAdd(&cursor[cellOf[n]], 1);
    packed[pos] = make_float4(xyz[n * 3 + 0], xyz[n * 3 + 1], xyz[n * 3 + 2],
                              __int_as_float(n));
}

// ---------------------------------------------------------------------------
// Grid ball query: one wave per query. Collect all in-ball candidates from
// 3x3x3 neighbor cells (9 contiguous z-runs) into LDS, then register-bitonic
// sort 128 slots (2/lane) to get the smallest 32 indices ascending.
// ---------------------------------------------------------------------------
__device__ __forceinline__ void ce_shfl(int& r0, int& r1, int j,
                                        bool asc0, bool asc1, int lane) {
    const int o0 = __shfl_xor(r0, j);
    const int o1 = __shfl_xor(r1, j);
    const bool lower = (lane & j) == 0;
    r0 = (lower == asc0) ? min(r0, o0) : max(r0, o0);
    r1 = (lower == asc1) ? min(r1, o1) : max(r1, o1);
}

__global__ __launch_bounds__(256) void grid_query_kernel(
        const float4* __restrict__ packed,     // (NPTS) cell-sorted {x,y,z,idx}
        const int*    __restrict__ cellStart,  // (NCELL+1)
        const float*  __restrict__ new_xyz,    // (B*P,3)
        int*   __restrict__ idxOut,            // (B*P, NS)
        float* __restrict__ idnOut) {          // (B*P, NS) as float
    const float R2 = (float)(0.08 * 0.08);

    const int wid  = threadIdx.x >> 6;
    const int lane = threadIdx.x & 63;
    const int q    = blockIdx.x * 4 + wid;

    __shared__ int cand[4][CAND_CAP];

    const float qx = new_xyz[q * 3 + 0];
    const float qy = new_xyz[q * 3 + 1];
    const float qz = new_xyz[q * 3 + 2];
    const float q2 = sq3(qx, qy, qz);

    const int cx = min(max((int)(qx * (float)GRID), 0), GRID - 1);
    const int cy = min(max((int)(qy * (float)GRID), 0), GRID - 1);
    const int cz = min(max((int)(qz * (float)GRID), 0), GRID - 1);

    const int xlo = max(cx - 1, 0), xhi = min(cx + 1, GRID - 1);
    const int ylo = max(cy - 1, 0), yhi = min(cy + 1, GRID - 1);
    const int zlo = max(cz - 1, 0), zhi = min(cz + 1, GRID - 1);

    const unsigned long long lt = (1ull << lane) - 1ull;
    int cnt = 0;  // wave-uniform

    for (int dx = xlo; dx <= xhi; ++dx) {
        for (int dy = ylo; dy <= yhi; ++dy) {
            const int row = (dx * GRID + dy) * GRID;
            const int s0 = cellStart[row + zlo];
            const int s1 = cellStart[row + zhi + 1];
            for (int base = s0; base < s1; base += 64) {
                const int i = base + lane;
                bool inball = false;
                int  pid = 0;
                if (i < s1) {
                    const float4 p = packed[i];
                    pid = __float_as_int(p.w);
                    const float x2 = sq3(p.x, p.y, p.z);
                    const float cross = __fadd_rn(
                        __fadd_rn(__fmul_rn(qx, p.x), __fmul_rn(qy, p.y)),
                        __fmul_rn(qz, p.z));
                    const float d2 = __fsub_rn(__fadd_rn(q2, x2),
                                               __fmul_rn(2.0f, cross));
                    inball = d2 < R2;
                }
                const unsigned long long m = __ballot(inball);
                if (inball) {
                    const int pos = cnt + __popcll(m & lt);
                    if (pos < CAND_CAP) cand[wid][pos] = pid;
                }
                cnt += __popcll(m);
            }
        }
    }

    __threadfence_block();   // drain LDS writes; wave-lockstep makes this enough

    const int M = min(cnt, CAND_CAP);
    int r0 = (lane      < M) ? cand[wid][lane]      : 0x7fffffff;
    int r1 = (lane + 64 < M) ? cand[wid][lane + 64] : 0x7fffffff;

    // Bitonic sort of 128 elements: element l -> r0 of lane l, element l+64 -> r1.
    #pragma unroll
    for (int k = 2; k <= 64; k <<= 1) {
        #pragma unroll
        for (int j = k >> 1; j >= 1; j >>= 1) {
            const bool asc0 = ((lane & k) == 0);
            const bool asc1 = (((lane | 64) & k) == 0);
            ce_shfl(r0, r1, j, asc0, asc1, lane);
        }
    }
    { const int lo = min(r0, r1), hi = max(r0, r1); r0 = lo; r1 = hi; }  // k=128, j=64
    #pragma unroll
    for (int j = 32; j >= 1; j >>= 1) ce_shfl(r0, r1, j, true, true, lane);

    // r0 of lane l == sorted[l]; lanes 0..31 hold the 32 smallest indices.
    const int nf = min(cnt, NS);
    const int first = __shfl(r0, 0);
    if (lane < NS) {
        int v; float fl;
        if (cnt == 0) { v = 0; fl = 1.0f; }
        else { v = (lane < nf) ? r0 : first; fl = (lane < nf) ? 1.0f : 0.0f; }
        idxOut[q * NS + lane] = v;
        idnOut[q * NS + lane] = fl;
    }
}

// ---------------------------------------------------------------------------
// Brute-force fallback (round-0 kernel) if workspace is too small for grid
// ---------------------------------------------------------------------------
__global__ __launch_bounds__(256) void ball_query_kernel(
        const float* __restrict__ xyz, const float* __restrict__ new_xyz,
        int* __restrict__ idxOut, float* __restrict__ idnOut) {
    const float R2 = (float)(0.08 * 0.08);
    const int wid  = threadIdx.x >> 6;
    const int lane = threadIdx.x & 63;
    const int q    = blockIdx.x * 4 + wid;
    __shared__ int buf[4][NS];
    const float qx = new_xyz[q * 3 + 0];
    const float qy = new_xyz[q * 3 + 1];
    const float qz = new_xyz[q * 3 + 2];
    const float q2 = sq3(qx, qy, qz);
    int cnt = 0;
    for (int base = 0; base < NPTS; base += 64) {
        const int i = base + lane;
        bool inball = false;
        if (i < NPTS) {
            const float px = xyz[i * 3 + 0], py = xyz[i * 3 + 1], pz = xyz[i * 3 + 2];
            const float x2 = sq3(px, py, pz);
            const float cross = __fadd_rn(
                __fadd_rn(__fmul_rn(qx, px), __fmul_rn(qy, py)), __fmul_rn(qz, pz));
            const float d2 = __fsub_rn(__fadd_rn(q2, x2), __fmul_rn(2.0f, cross));
            inball = d2 < R2;
        }
        const unsigned long long m = __ballot(inball);
        if (inball) {
            const int pos = cnt + __popcll(m & ((1ull << lane) - 1ull));
            if (pos < NS) buf[wid][pos] = i;
        }
        cnt += __popcll(m);
        if (cnt >= NS) break;
    }
    __syncthreads();
    if (lane < NS) {
        const int nf = (cnt < NS) ? cnt : NS;
        int v; float fl;
        if (nf == 0) { v = 0; fl = 1.0f; }
        else { v = (lane < nf) ? buf[wid][lane] : buf[wid][0];
               fl = (lane < nf) ? 1.0f : 0.0f; }
        idxOut[q * NS + lane] = v;
        idnOut[q * NS + lane] = fl;
    }
}

// ---------------------------------------------------------------------------
// Transpose features (C,N) -> (N,C)
// ---------------------------------------------------------------------------
__global__ void feat_transpose_kernel(const float* __restrict__ features,
                                      float* __restrict__ featT) {
    __shared__ float tile[64][65];
    const int n0 = blockIdx.x * 64;
    const int t  = threadIdx.x;
    const int nn   = t & 63;
    const int cgrp = t >> 6;
    for (int k = 0; k < 16; ++k) {
        const int cc = cgrp * 16 + k;
        const int n  = n0 + nn;
        if (n < NPTS) tile[cc][nn] = features[cc * NPTS + n];
    }
    __syncthreads();
    const int cc2  = t & 63;
    const int ngrp = t >> 6;
    for (int k = 0; k < 16; ++k) {
        const int nn2 = ngrp * 16 + k;
        const int n   = n0 + nn2;
        if (n < NPTS) featT[n * NC + cc2] = tile[cc2][nn2];
    }
}

// ---------------------------------------------------------------------------
// Group: one block (256 thr) per query
// ---------------------------------------------------------------------------
__global__ __launch_bounds__(256) void group_kernel(
        const float* __restrict__ xyz,
        const float* __restrict__ new_xyz,
        const float* __restrict__ features,
        const float* __restrict__ featT,
        const int*   __restrict__ idx,
        float* __restrict__ out,
        int haveFeatT) {
    const int q = blockIdx.x;
    const int b = q >> 11;
    const int p = q & (NQ - 1);

    __shared__ int   sidx[NS];
    __shared__ float sq[3];

    const int t = threadIdx.x;
    if (t < NS) sidx[t] = idx[q * NS + t];
    if (t < 3)  sq[t]   = new_xyz[q * 3 + t];
    __syncthreads();

    if (t < 96) {
        const int d = t >> 5;
        const int s = t & 31;
        const int id = sidx[s];
        const int o = ((b * NCOUT + d) * NQ + p) * NS + s;
        out[o] = __fsub_rn(xyz[id * 3 + d], sq[d]);
    }

    const int s  = t & 31;
    const int c4 = t >> 5;
    const int id = sidx[s];
    const int CH_STRIDE = NQ * NS;

    if (haveFeatT) {
        const float4* ft = (const float4*)featT;
        #pragma unroll
        for (int h = 0; h < 2; ++h) {
            const int cc4 = c4 + h * 8;
            const float4 v = ft[id * (NC / 4) + cc4];
            const int cbase = cc4 * 4;
            const int o = ((b * NCOUT + 3 + cbase) * NQ + p) * NS + s;
            out[o]                 = v.x;
            out[o + 1 * CH_STRIDE] = v.y;
            out[o + 2 * CH_STRIDE] = v.z;
            out[o + 3 * CH_STRIDE] = v.w;
        }
    } else {
        #pragma unroll
        for (int h = 0; h < 2; ++h) {
            const int cbase = (c4 + h * 8) * 4;
            #pragma unroll
            for (int k = 0; k < 4; ++k) {
                const int c = cbase + k;
                const int o = ((b * NCOUT + 3 + c) * NQ + p) * NS + s;
                out[o] = features[c * NPTS + id];
            }
        }
    }
}

extern "C" void kernel_launch(void* const* d_in, const int* in_sizes, int n_in,
                              void* d_out, int out_size, void* d_ws, size_t ws_size,
                              hipStream_t stream) {
    const float* xyz      = (const float*)d_in[0];
    const float* new_xyz  = (const float*)d_in[1];
    const float* features = (const float*)d_in[2];

    float* out     = (float*)d_out;
    float* idn_out = out + NF_ELEMS;

    // workspace layout (byte offsets, 256-aligned)
    const size_t OFF_IDX    = 0;                       // 4096*32*4   = 524288
    const size_t OFF_FEATT  = 524288;                  // 20000*64*4  = 5120000
    const size_t OFF_CNT    = 5644288;                 // 1728*4      (pad 7168)
    const size_t OFF_START  = 5651456;                 // 1729*4      (pad 7168)
    const size_t OFF_CURSOR = 5658624;                 // 1728*4      (pad 7168)
    const size_t OFF_CELLOF = 5665792;                 // 20000*4     = 80000
    const size_t OFF_PACKED = 5745792;                 // 20000*16    = 320000
    const size_t GRID_TOTAL = 6065792;
    const size_t FEATT_END  = 5644288;

    int*    d_idx    = (int*)((char*)d_ws + OFF_IDX);
    float*  d_featT  = (float*)((char*)d_ws + OFF_FEATT);
    int*    d_cnt    = (int*)((char*)d_ws + OFF_CNT);
    int*    d_start  = (int*)((char*)d_ws + OFF_START);
    int*    d_cursor = (int*)((char*)d_ws + OFF_CURSOR);
    int*    d_cellOf = (int*)((char*)d_ws + OFF_CELLOF);
    float4* d_packed = (float4*)((char*)d_ws + OFF_PACKED);

    const int haveGrid  = (ws_size >= GRID_TOTAL) ? 1 : 0;
    const int haveFeatT = (ws_size >= FEATT_END) ? 1 : 0;

    if (haveFeatT) {
        feat_transpose_kernel<<<(NPTS + 63) / 64, 256, 0, stream>>>(features, d_featT);
    }

    if (haveGrid) {
        zero_counts_kernel<<<1, 256, 0, stream>>>(d_cnt);
        cell_count_kernel<<<(NPTS + 255) / 256, 256, 0, stream>>>(xyz, d_cellOf, d_cnt);
        scan_kernel<<<1, 256, 0, stream>>>(d_cnt, d_start, d_cursor);
        scatter_kernel<<<(NPTS + 255) / 256, 256, 0, stream>>>(xyz, d_cellOf, d_cursor, d_packed);
        grid_query_kernel<<<NQTOT / 4, 256, 0, stream>>>(d_packed, d_start, new_xyz,
                                                         d_idx, idn_out);
    } else {
        ball_query_kernel<<<NQTOT / 4, 256, 0, stream>>>(xyz, new_xyz, d_idx, idn_out);
    }

    group_kernel<<<NQTOT, 256, 0, stream>>>(xyz, new_xyz, features,
                                            haveFeatT ? d_featT : nullptr,
                                            d_idx, out, haveFeatT);
}

// Round 3
// 99.978 us; speedup vs baseline: 1.9849x; 1.0708x over previous
//
#include <hip/hip_runtime.h>
#include <hip/hip_bf16.h>

// Problem constants (from reference setup_inputs)
#define NPTS   20000
#define BATCH  2
#define NQ     2048          // P
#define NS     32            // NSAMPLE
#define NC     64            // feature channels
#define NCOUT  67            // 3 + 64
#define NQTOT  (BATCH * NQ)  // 4096 queries
#define NF_ELEMS (BATCH * NCOUT * NQ * NS)   // 17,563,648

// Spatial grid: cell edge 1/12 = 0.08333 >= radius 0.08 -> 3x3x3 covers ball
#define GRID   12
#define NCELL  (GRID * GRID * GRID)   // 1728
#define CAND_CAP 128                  // max in-ball candidates kept (mean ~43, max ~75)

// -------- exact-fp32 helpers (no FMA contraction; replicate numpy order) ----
__device__ __forceinline__ float sq3(float a, float b, float c) {
    return __fadd_rn(__fadd_rn(__fmul_rn(a, a), __fmul_rn(b, b)), __fmul_rn(c, c));
}

// ---------------------------------------------------------------------------
// zero cell counts (1 block)
// ---------------------------------------------------------------------------
__global__ __launch_bounds__(256) void zero_counts_kernel(int* __restrict__ cnt) {
    const int t = threadIdx.x;
    #pragma unroll
    for (int i = 0; i < 7; ++i) {
        const int c = t * 7 + i;
        if (c < NCELL) cnt[c] = 0;
    }
}

// ---------------------------------------------------------------------------
// Fused: transpose features (C,N)->(N,C) tile + bin this tile's 64 points
// ---------------------------------------------------------------------------
__global__ __launch_bounds__(256) void transpose_count_kernel(
        const float* __restrict__ features, const float* __restrict__ xyz,
        float* __restrict__ featT, int* __restrict__ cellOf,
        int* __restrict__ cnt) {
    __shared__ float tile[64][65];
    const int n0 = blockIdx.x * 64;
    const int t  = threadIdx.x;

    // cell binning for this tile's 64 points (threads 0..63)
    if (t < 64) {
        const int n = n0 + t;
        if (n < NPTS) {
            const float x = xyz[n * 3 + 0];
            const float y = xyz[n * 3 + 1];
            const float z = xyz[n * 3 + 2];
            const int cx = min(max((int)(x * (float)GRID), 0), GRID - 1);
            const int cy = min(max((int)(y * (float)GRID), 0), GRID - 1);
            const int cz = min(max((int)(z * (float)GRID), 0), GRID - 1);
            const int cell = (cx * GRID + cy) * GRID + cz;
            cellOf[n] = cell;
            atomicAdd(&cnt[cell], 1);
        }
    }

    // transpose tile
    const int nn   = t & 63;
    const int cgrp = t >> 6;
    for (int k = 0; k < 16; ++k) {
        const int cc = cgrp * 16 + k;
        const int n  = n0 + nn;
        if (n < NPTS) tile[cc][nn] = features[cc * NPTS + n];
    }
    __syncthreads();
    const int cc2  = t & 63;
    const int ngrp = t >> 6;
    for (int k = 0; k < 16; ++k) {
        const int nn2 = ngrp * 16 + k;
        const int n   = n0 + nn2;
        if (n < NPTS) featT[n * NC + cc2] = tile[cc2][nn2];
    }
}

// ---------------------------------------------------------------------------
// Exclusive scan over 1728 cell counts (1 block)
// ---------------------------------------------------------------------------
__global__ __launch_bounds__(256) void scan_kernel(
        const int* __restrict__ cnt, int* __restrict__ start,
        int* __restrict__ cursor) {
    __shared__ int s[256];
    const int t = threadIdx.x;
    int loc[7];
    int sum = 0;
    #pragma unroll
    for (int i = 0; i < 7; ++i) {
        const int c = t * 7 + i;
        const int v = (c < NCELL) ? cnt[c] : 0;
        loc[i] = sum;
        sum += v;
    }
    s[t] = sum;
    __syncthreads();
    for (int off = 1; off < 256; off <<= 1) {
        const int v = (t >= off) ? s[t - off] : 0;
        __syncthreads();
        s[t] += v;
        __syncthreads();
    }
    const int excl = s[t] - sum;
    #pragma unroll
    for (int i = 0; i < 7; ++i) {
        const int c = t * 7 + i;
        if (c < NCELL) {
            const int val = excl + loc[i];
            start[c]  = val;
            cursor[c] = val;
        }
    }
    if (t == 255) start[NCELL] = s[255];
}

// ---------------------------------------------------------------------------
// Scatter points into cell-sorted packed array {x,y,z,idx}
// ---------------------------------------------------------------------------
__global__ __launch_bounds__(256) void scatter_kernel(
        const float* __restrict__ xyz, const int* __restrict__ cellOf,
        int* __restrict__ cursor, float4* __restrict__ packed) {
    const int n = blockIdx.x * 256 + threadIdx.x;
    if (n >= NPTS) return;
    const int pos = atomicAdd(&cursor[cellOf[n]], 1);
    packed[pos] = make_float4(xyz[n * 3 + 0], xyz[n * 3 + 1], xyz[n * 3 + 2],
                              __int_as_float(n));
}

// ---------------------------------------------------------------------------
// bitonic compare-exchange via shfl_xor (2 elements per lane)
// ---------------------------------------------------------------------------
__device__ __forceinline__ void ce_shfl(int& r0, int& r1, int j,
                                        bool asc0, bool asc1, int lane) {
    const int o0 = __shfl_xor(r0, j);
    const int o1 = __shfl_xor(r1, j);
    const bool lower = (lane & j) == 0;
    r0 = (lower == asc0) ? min(r0, o0) : max(r0, o0);
    r1 = (lower == asc1) ? min(r1, o1) : max(r1, o1);
}

// ---------------------------------------------------------------------------
// FUSED query + group: one wave per query.
//  phase 1: grid walk, collect in-ball pids to LDS, bitonic top-32 ascending
//  phase 2: gather xyz/featT for the 32 neighbors, write output slice + idn
// ---------------------------------------------------------------------------
__global__ __launch_bounds__(256) void query_group_kernel(
        const float4* __restrict__ packed,     // (NPTS) cell-sorted {x,y,z,idx}
        const int*    __restrict__ cellStart,  // (NCELL+1)
        const float*  __restrict__ new_xyz,    // (B*P,3)
        const float*  __restrict__ xyz,        // (N,3)
        const float4* __restrict__ featT4,     // (N, NC/4) float4 view
        float* __restrict__ out,               // (B,67,P,S)
        float* __restrict__ idnOut) {          // (B,P,S) as float
    const float R2 = (float)(0.08 * 0.08);

    const int wid  = threadIdx.x >> 6;
    const int lane = threadIdx.x & 63;
    const int q    = blockIdx.x * 4 + wid;     // grid 1024 -> q < 4096

    __shared__ int cand[4][CAND_CAP];
    __shared__ int sidx[4][NS];

    const float qx = new_xyz[q * 3 + 0];
    const float qy = new_xyz[q * 3 + 1];
    const float qz = new_xyz[q * 3 + 2];
    const float q2 = sq3(qx, qy, qz);

    const int cx = min(max((int)(qx * (float)GRID), 0), GRID - 1);
    const int cy = min(max((int)(qy * (float)GRID), 0), GRID - 1);
    const int cz = min(max((int)(qz * (float)GRID), 0), GRID - 1);

    const int xlo = max(cx - 1, 0), xhi = min(cx + 1, GRID - 1);
    const int ylo = max(cy - 1, 0), yhi = min(cy + 1, GRID - 1);
    const int zlo = max(cz - 1, 0), zhi = min(cz + 1, GRID - 1);

    const unsigned long long lt = (1ull << lane) - 1ull;
    int cnt = 0;  // wave-uniform

    for (int dx = xlo; dx <= xhi; ++dx) {
        for (int dy = ylo; dy <= yhi; ++dy) {
            const int row = (dx * GRID + dy) * GRID;
            const int s0 = cellStart[row + zlo];
            const int s1 = cellStart[row + zhi + 1];
            for (int base = s0; base < s1; base += 64) {
                const int i = base + lane;
                bool inball = false;
                int  pid = 0;
                if (i < s1) {
                    const float4 p = packed[i];
                    pid = __float_as_int(p.w);
                    const float x2 = sq3(p.x, p.y, p.z);
                    const float cross = __fadd_rn(
                        __fadd_rn(__fmul_rn(qx, p.x), __fmul_rn(qy, p.y)),
                        __fmul_rn(qz, p.z));
                    const float d2 = __fsub_rn(__fadd_rn(q2, x2),
                                               __fmul_rn(2.0f, cross));
                    inball = d2 < R2;
                }
                const unsigned long long m = __ballot(inball);
                if (inball) {
                    const int pos = cnt + __popcll(m & lt);
                    if (pos < CAND_CAP) cand[wid][pos] = pid;
                }
                cnt += __popcll(m);
            }
        }
    }

    __threadfence_block();   // drain this wave's LDS writes before re-read

    const int M = min(cnt, CAND_CAP);
    int r0 = (lane      < M) ? cand[wid][lane]      : 0x7fffffff;
    int r1 = (lane + 64 < M) ? cand[wid][lane + 64] : 0x7fffffff;

    // bitonic sort of 128 elements (element l -> lane l r0; l+64 -> r1)
    #pragma unroll
    for (int k = 2; k <= 64; k <<= 1) {
        #pragma unroll
        for (int j = k >> 1; j >= 1; j >>= 1) {
            const bool asc0 = ((lane & k) == 0);
            const bool asc1 = (((lane | 64) & k) == 0);
            ce_shfl(r0, r1, j, asc0, asc1, lane);
        }
    }
    { const int lo = min(r0, r1), hi = max(r0, r1); r0 = lo; r1 = hi; }  // k=128,j=64
    #pragma unroll
    for (int j = 32; j >= 1; j >>= 1) ce_shfl(r0, r1, j, true, true, lane);

    // lanes 0..31 of r0 = 32 smallest in-ball indices, ascending
    const int nf = min(cnt, NS);
    const int first = __shfl(r0, 0);
    if (lane < NS) {
        int v; float fl;
        if (cnt == 0) { v = 0; fl = 1.0f; }
        else { v = (lane < nf) ? r0 : first; fl = (lane < nf) ? 1.0f : 0.0f; }
        sidx[wid][lane] = v;
        idnOut[q * NS + lane] = fl;
    }

    __threadfence_block();   // sidx visible to this wave's re-read

    // ---- group phase ----
    const int b = q >> 11;             // q / 2048
    const int p = q & (NQ - 1);
    const int CH_STRIDE = NQ * NS;     // 65536

    // xyz part: 3 channels x 32 samples
    for (int k = lane; k < 96; k += 64) {
        const int d = k >> 5;
        const int s = k & 31;
        const int id = sidx[wid][s];
        const float qd = (d == 0) ? qx : ((d == 1) ? qy : qz);
        out[((b * NCOUT + d) * NQ + p) * NS + s] = __fsub_rn(xyz[id * 3 + d], qd);
    }

    // feature part: 64 channels x 32 samples; lane = (half, s)
    const int s    = lane & 31;
    const int half = lane >> 5;        // 0/1
    const int id   = sidx[wid][s];
    const int rowbase = id * (NC / 4);
    #pragma unroll
    for (int k = 0; k < 8; ++k) {
        const int cc4 = k * 2 + half;  // 0..15
        const float4 vf = featT4[rowbase + cc4];
        const int o = ((b * NCOUT + 3 + cc4 * 4) * NQ + p) * NS + s;
        out[o]                 = vf.x;
        out[o + 1 * CH_STRIDE] = vf.y;
        out[o + 2 * CH_STRIDE] = vf.z;
        out[o + 3 * CH_STRIDE] = vf.w;
    }
}

extern "C" void kernel_launch(void* const* d_in, const int* in_sizes, int n_in,
                              void* d_out, int out_size, void* d_ws, size_t ws_size,
                              hipStream_t stream) {
    const float* xyz      = (const float*)d_in[0];
    const float* new_xyz  = (const float*)d_in[1];
    const float* features = (const float*)d_in[2];

    float* out     = (float*)d_out;
    float* idn_out = out + NF_ELEMS;

    // workspace layout (byte offsets; featT 16B-aligned at 0, packed 16B-aligned)
    const size_t OFF_FEATT  = 0;           // 20000*64*4 = 5,120,000
    const size_t OFF_CNT    = 5120000;     // 1728*4 (pad 7168)
    const size_t OFF_START  = 5127168;     // 1729*4 (pad 7168)
    const size_t OFF_CURSOR = 5134336;     // 1728*4 (pad 7168)
    const size_t OFF_CELLOF = 5141504;     // 20000*4 = 80,000
    const size_t OFF_PACKED = 5221504;     // 20000*16 = 320,000 (16-aligned)
    // total = 5,541,504 bytes (< the ~6 MB ws that R2 already used successfully)

    float*  d_featT  = (float*)((char*)d_ws + OFF_FEATT);
    int*    d_cnt    = (int*)((char*)d_ws + OFF_CNT);
    int*    d_start  = (int*)((char*)d_ws + OFF_START);
    int*    d_cursor = (int*)((char*)d_ws + OFF_CURSOR);
    int*    d_cellOf = (int*)((char*)d_ws + OFF_CELLOF);
    float4* d_packed = (float4*)((char*)d_ws + OFF_PACKED);

    zero_counts_kernel<<<1, 256, 0, stream>>>(d_cnt);
    transpose_count_kernel<<<(NPTS + 63) / 64, 256, 0, stream>>>(
        features, xyz, d_featT, d_cellOf, d_cnt);
    scan_kernel<<<1, 256, 0, stream>>>(d_cnt, d_start, d_cursor);
    scatter_kernel<<<(NPTS + 255) / 256, 256, 0, stream>>>(
        xyz, d_cellOf, d_cursor, d_packed);
    query_group_kernel<<<NQTOT / 4, 256, 0, stream>>>(
        d_packed, d_start, new_xyz, xyz, (const float4*)d_featT, out, idn_out);
}